// Round 3
// baseline (221.372 us; speedup 1.0000x reference)
//
#include <hip/hip_runtime.h>
#include <hip/hip_bf16.h>
#include <stdint.h>

#define B_SZ 8192
#define D_SZ 1024
#define BM 128
#define BN 128
#define BK 32
#define KTILES (D_SZ / BK)  // 32

typedef __attribute__((ext_vector_type(4))) float f32x4;
typedef __attribute__((ext_vector_type(8))) short short8;

__device__ __forceinline__ ushort f2bf(float f) {
  union { float f; uint32_t u; } c; c.f = f;
  uint32_t u = c.u;
  return (ushort)((u + 0x7fffu + ((u >> 16) & 1u)) >> 16);  // RNE
}

__device__ __forceinline__ void gload_lds16(const void* g, void* l) {
  __builtin_amdgcn_global_load_lds(
      (const __attribute__((address_space(1))) void*)g,
      (__attribute__((address_space(3))) void*)l, 16, 0, 0);
}

// Pass 1: fp32 -> bf16 conversion, fp32 row sum-of-squares, init min arrays to +inf.
// One block per row; blocks [0,8192) = X rows, [8192,16384) = Y rows.
extern "C" __global__ __launch_bounds__(256)
void prep_k(const float* __restrict__ X, const float* __restrict__ Y,
            ushort* __restrict__ Xb, ushort* __restrict__ Yb,
            float* __restrict__ sq, float* __restrict__ mins) {
  const int b = blockIdx.x;
  const int t = threadIdx.x;
  const int row = b & (B_SZ - 1);
  const float* src = (b < B_SZ) ? X : Y;
  ushort* dst = (b < B_SZ) ? Xb : Yb;
  const float4 v = reinterpret_cast<const float4*>(src + (size_t)row * D_SZ)[t];
  float ss = v.x * v.x + v.y * v.y + v.z * v.z + v.w * v.w;
  ushort4 o;
  o.x = f2bf(v.x); o.y = f2bf(v.y); o.z = f2bf(v.z); o.w = f2bf(v.w);
  reinterpret_cast<ushort4*>(dst + (size_t)row * D_SZ)[t] = o;
#pragma unroll
  for (int m = 1; m < 64; m <<= 1) ss += __shfl_xor(ss, m);
  __shared__ float red[4];
  if ((t & 63) == 0) red[t >> 6] = ss;
  __syncthreads();
  if (t == 0) {
    sq[b] = red[0] + red[1] + red[2] + red[3];
    mins[b] = __builtin_inff();
  }
}

// Pass 2: tiled bf16 GEMM (cross = X·Y^T), fused mse + min epilogue.
// 128x128 tile, BK=32, 4 waves (2x2), 4x4 fragments of mfma_f32_16x16x32_bf16.
extern "C" __global__ __launch_bounds__(256)
void gemm_min_k(const ushort* __restrict__ Xb, const ushort* __restrict__ Yb,
                const float* __restrict__ sqx, const float* __restrict__ sqy,
                float* __restrict__ rowmin, float* __restrict__ colmin) {
  __shared__ ushort lds[2][2][BM * BK];  // [dbuf][A/B][128*32] = 32 KB
  const int tid  = threadIdx.x;
  const int wave = tid >> 6;
  const int lane = tid & 63;
  const int q    = lane >> 4;
  const int r    = lane & 15;
  const int wr   = wave >> 1;
  const int wc   = wave & 1;

  const int bi = blockIdx.x, bj = blockIdx.y;
  const size_t ar0 = (size_t)bi * BM;
  const size_t br0 = (size_t)bj * BN;
  const ushort* Abase = Xb + ar0 * D_SZ;
  const ushort* Bbase = Yb + br0 * D_SZ;

  // staging geometry: tile = 512 16B-units; unit L -> row=L>>2, u=L&3.
  // wave w stages units [w*64, w*64+64) and [(w+4)*64, ...): linear LDS dest.
  const int L0 = wave * 64 + lane;
  const int L1 = (wave + 4) * 64 + lane;
  const int row0 = L0 >> 2, u0 = L0 & 3;
  const int row1 = L1 >> 2, u1 = L1 & 3;

  f32x4 acc[4][4];
#pragma unroll
  for (int m = 0; m < 4; ++m)
#pragma unroll
    for (int n = 0; n < 4; ++n)
      acc[m][n] = (f32x4){0.f, 0.f, 0.f, 0.f};

  auto stage = [&](int buf, int kt) {
    const int k0 = kt * BK;
    gload_lds16(Abase + (size_t)row0 * D_SZ + k0 + u0 * 8, &lds[buf][0][wave * 512]);
    gload_lds16(Abase + (size_t)row1 * D_SZ + k0 + u1 * 8, &lds[buf][0][(wave + 4) * 512]);
    gload_lds16(Bbase + (size_t)row0 * D_SZ + k0 + u0 * 8, &lds[buf][1][wave * 512]);
    gload_lds16(Bbase + (size_t)row1 * D_SZ + k0 + u1 * 8, &lds[buf][1][(wave + 4) * 512]);
  };

  stage(0, 0);
  __syncthreads();  // vmcnt(0) drain: buf0 ready
  int buf = 0;
  for (int kt = 0; kt < KTILES; ++kt) {
    if (kt + 1 < KTILES) stage(buf ^ 1, kt + 1);  // async prefetch overlaps compute
    short8 a[4], bfr[4];
#pragma unroll
    for (int m = 0; m < 4; ++m)
      a[m] = *(const short8*)&lds[buf][0][(wr * 64 + m * 16 + r) * BK + q * 8];
#pragma unroll
    for (int n = 0; n < 4; ++n)
      bfr[n] = *(const short8*)&lds[buf][1][(wc * 64 + n * 16 + r) * BK + q * 8];
#pragma unroll
    for (int m = 0; m < 4; ++m)
#pragma unroll
      for (int n = 0; n < 4; ++n)
        acc[m][n] = __builtin_amdgcn_mfma_f32_16x16x32_bf16(a[m], bfr[n], acc[m][n], 0, 0, 0);
    __syncthreads();  // drains prefetch vmcnt + protects buf reuse
    buf ^= 1;
  }

  // ---- fused epilogue: mse + tile-local min reductions ----
  const float inv_d = 1.0f / (float)D_SZ;
  float sy[4];
#pragma unroll
  for (int n = 0; n < 4; ++n) sy[n] = sqy[br0 + wc * 64 + n * 16 + r];
  float sx[4][4];
#pragma unroll
  for (int m = 0; m < 4; ++m)
#pragma unroll
    for (int j = 0; j < 4; ++j) sx[m][j] = sqx[ar0 + wr * 64 + m * 16 + 4 * q + j];

  float rm[4][4], cm[4];
#pragma unroll
  for (int n = 0; n < 4; ++n) cm[n] = __builtin_inff();
#pragma unroll
  for (int m = 0; m < 4; ++m) {
#pragma unroll
    for (int j = 0; j < 4; ++j) {
      float best = __builtin_inff();
#pragma unroll
      for (int n = 0; n < 4; ++n) {
        float mse = (sx[m][j] + sy[n] - 2.0f * acc[m][n][j]) * inv_d;
        best = fminf(best, mse);
        cm[n] = fminf(cm[n], mse);
      }
      rm[m][j] = best;
    }
  }
  // rowmin: reduce over the 16 r-lanes (cols); lanes r==0 end up authoritative
#pragma unroll
  for (int m = 0; m < 4; ++m)
#pragma unroll
    for (int j = 0; j < 4; ++j) {
      float v = rm[m][j];
      v = fminf(v, __shfl_xor(v, 1));
      v = fminf(v, __shfl_xor(v, 2));
      v = fminf(v, __shfl_xor(v, 4));
      v = fminf(v, __shfl_xor(v, 8));
      rm[m][j] = v;
    }
  // colmin: reduce over the 4 q-groups (rows)
#pragma unroll
  for (int n = 0; n < 4; ++n) {
    float v = cm[n];
    v = fminf(v, __shfl_xor(v, 16));
    v = fminf(v, __shfl_xor(v, 32));
    cm[n] = v;
  }

  // cross-wave combine in LDS (tiles are dead after last barrier)
  float* red = (float*)&lds[0][0][0];  // [0..255]=row side, [256..511]=col side
  if (r == 0) {
#pragma unroll
    for (int m = 0; m < 4; ++m)
#pragma unroll
      for (int j = 0; j < 4; ++j)
        red[wc * 128 + wr * 64 + m * 16 + 4 * q + j] = rm[m][j];
  }
  if (q == 0) {
#pragma unroll
    for (int n = 0; n < 4; ++n)
      red[256 + wr * 128 + wc * 64 + n * 16 + r] = cm[n];
  }
  __syncthreads();
  if (tid < 128) {
    float v = fminf(red[tid], red[128 + tid]);
    atomicMin((int*)&rowmin[ar0 + tid], __float_as_int(v));  // mse > 0 -> int order == float order
  } else {
    const int c = tid - 128;
    float v = fminf(red[256 + c], red[256 + 128 + c]);
    atomicMin((int*)&colmin[br0 + c], __float_as_int(v));
  }
}

// Pass 3: mean of the 16384 mins -> scalar
extern "C" __global__ __launch_bounds__(256)
void final_k(const float* __restrict__ mins, float* __restrict__ out) {
  float s = 0.f;
  for (int i = threadIdx.x; i < 2 * B_SZ; i += 256) s += mins[i];
#pragma unroll
  for (int m = 1; m < 64; m <<= 1) s += __shfl_xor(s, m);
  __shared__ float red[4];
  if ((threadIdx.x & 63) == 0) red[threadIdx.x >> 6] = s;
  __syncthreads();
  if (threadIdx.x == 0)
    out[0] = (red[0] + red[1] + red[2] + red[3]) * (1.0f / (float)(2 * B_SZ));
}

extern "C" void kernel_launch(void* const* d_in, const int* in_sizes, int n_in,
                              void* d_out, int out_size, void* d_ws, size_t ws_size,
                              hipStream_t stream) {
  const float* X = (const float*)d_in[0];
  const float* Y = (const float*)d_in[1];
  char* ws = (char*)d_ws;
  ushort* Xb = (ushort*)ws;                                   // 16 MB
  ushort* Yb = (ushort*)(ws + (size_t)16 * 1024 * 1024);      // 16 MB
  float* sq  = (float*)(ws + (size_t)32 * 1024 * 1024);       // sqx[8192] ++ sqy[8192]
  float* mins = sq + 2 * B_SZ;                                // rowmin[8192] ++ colmin[8192]
  float* out = (float*)d_out;

  prep_k<<<2 * B_SZ, 256, 0, stream>>>(X, Y, Xb, Yb, sq, mins);
  gemm_min_k<<<dim3(B_SZ / BM, B_SZ / BN), 256, 0, stream>>>(Xb, Yb, sq, sq + B_SZ,
                                                             mins, mins + B_SZ);
  final_k<<<1, 256, 0, stream>>>(mins, out);
}

// Round 4
// 175.624 us; speedup vs baseline: 1.2605x; 1.2605x over previous
//
#include <hip/hip_runtime.h>
#include <hip/hip_bf16.h>
#include <stdint.h>

#define B_SZ 8192
#define D_SZ 1024
#define BM 256
#define BN 256
#define BK 32
#define NKT (D_SZ / BK)  // 32 K-tiles

typedef __attribute__((ext_vector_type(4))) float f32x4;
typedef __attribute__((ext_vector_type(8))) short short8;

#define WAITVM(n) asm volatile("s_waitcnt vmcnt(" #n ")" ::: "memory")
#define SCHEDB() __builtin_amdgcn_sched_barrier(0)
#define BARRIER() do { SCHEDB(); __builtin_amdgcn_s_barrier(); SCHEDB(); } while (0)

__device__ __forceinline__ ushort f2bf(float f) {
  union { float f; uint32_t u; } c; c.f = f;
  uint32_t u = c.u;
  return (ushort)((u + 0x7fffu + ((u >> 16) & 1u)) >> 16);  // RNE
}

__device__ __forceinline__ void gload_lds16(const ushort* g, void* l) {
  __builtin_amdgcn_global_load_lds(
      (const __attribute__((address_space(1))) void*)g,
      (__attribute__((address_space(3))) void*)l, 16, 0, 0);
}

// Pass 1: fp32 -> bf16 conversion, fp32 row sum-of-squares, init mins to +inf.
extern "C" __global__ __launch_bounds__(256)
void prep_k(const float* __restrict__ X, const float* __restrict__ Y,
            ushort* __restrict__ Xb, ushort* __restrict__ Yb,
            float* __restrict__ sq, float* __restrict__ mins) {
  const int b = blockIdx.x;
  const int t = threadIdx.x;
  const int row = b & (B_SZ - 1);
  const float* src = (b < B_SZ) ? X : Y;
  ushort* dst = (b < B_SZ) ? Xb : Yb;
  const float4 v = reinterpret_cast<const float4*>(src + (size_t)row * D_SZ)[t];
  float ss = v.x * v.x + v.y * v.y + v.z * v.z + v.w * v.w;
  ushort4 o;
  o.x = f2bf(v.x); o.y = f2bf(v.y); o.z = f2bf(v.z); o.w = f2bf(v.w);
  reinterpret_cast<ushort4*>(dst + (size_t)row * D_SZ)[t] = o;
#pragma unroll
  for (int m = 1; m < 64; m <<= 1) ss += __shfl_xor(ss, m);
  __shared__ float red[4];
  if ((t & 63) == 0) red[t >> 6] = ss;
  __syncthreads();
  if (t == 0) {
    sq[b] = red[0] + red[1] + red[2] + red[3];
    mins[b] = __builtin_inff();
  }
}

// Pass 2: 256x256 tile, BK=32, 8 waves (2x4), 4-deep LDS ring, counted vmcnt.
// Per wave: 128x64 output = acc[8][4] of 16x16x32 bf16 fragments.
// LDS content swizzle: chunk slot s of row holds global k-chunk (s ^ ((row>>1)&3)).
// Applied on the *global source* (gload_lds dest is linear) and on ds_read addr.
extern "C" __global__ __launch_bounds__(512, 2)
void gemm_min_k(const ushort* __restrict__ Xb, const ushort* __restrict__ Yb,
                const float* __restrict__ sqx, const float* __restrict__ sqy,
                float* __restrict__ rowmin, float* __restrict__ colmin) {
  __shared__ ushort lds[4][2][BM * BK];  // 4 ring bufs x {A,B} x 256x32 bf16 = 128 KiB

  const int tid  = threadIdx.x;
  const int wave = tid >> 6;
  const int lane = tid & 63;
  const int q    = lane >> 4;    // 0..3
  const int r    = lane & 15;    // 0..15
  const int wr   = wave >> 2;    // 0..1  (M half)
  const int wc   = wave & 3;     // 0..3  (N quarter)
  const int sl   = q ^ ((r >> 1) & 3);  // swizzled ds_read slot (same for all frags)

  const size_t ar0 = (size_t)blockIdx.x * BM;
  const size_t br0 = (size_t)blockIdx.y * BN;
  const ushort* Ab = Xb + ar0 * D_SZ;
  const ushort* Bb = Yb + br0 * D_SZ;

  // staging geometry: per operand per K-tile = 256 rows x 32 cols bf16 = 16 KiB.
  // 2 gload_lds per wave per operand; instr i covers LDS bytes [wave*1024 + i*8192, +1024).
  // chunk c = wave*64 + i*512 + lane -> row=c>>2, slot=c&3; global k-chunk = slot ^ ((row>>1)&3).
  const int c0 = wave * 64 + lane;
  const int c1 = c0 + 512;
  const int r0 = c0 >> 2, r1 = c1 >> 2;
  const int s0 = (c0 & 3) ^ ((r0 >> 1) & 3);
  const int s1 = (c1 & 3) ^ ((r1 >> 1) & 3);
  const size_t ga0 = (size_t)r0 * D_SZ + s0 * 8;
  const size_t ga1 = (size_t)r1 * D_SZ + s1 * 8;
  const int ldsoff0 = wave * 1024;           // bytes
  const int ldsoff1 = wave * 1024 + 8192;

  f32x4 acc[8][4];
#pragma unroll
  for (int m = 0; m < 8; ++m)
#pragma unroll
    for (int n = 0; n < 4; ++n)
      acc[m][n] = (f32x4){0.f, 0.f, 0.f, 0.f};

  auto stage = [&](int kt) {
    const int b = kt & 3;
    const int ko = kt * BK;
    gload_lds16(Ab + ga0 + ko, (char*)&lds[b][0][0] + ldsoff0);
    gload_lds16(Ab + ga1 + ko, (char*)&lds[b][0][0] + ldsoff1);
    gload_lds16(Bb + ga0 + ko, (char*)&lds[b][1][0] + ldsoff0);
    gload_lds16(Bb + ga1 + ko, (char*)&lds[b][1][0] + ldsoff1);
  };

  auto compute = [&](int kt) {
    const int b = kt & 3;
    const ushort* LA = &lds[b][0][0];
    const ushort* LB = &lds[b][1][0];
    short8 a[8], bb[4];
#pragma unroll
    for (int m = 0; m < 8; ++m)
      a[m] = *(const short8*)&LA[(wr * 128 + m * 16 + r) * BK + sl * 8];
#pragma unroll
    for (int n = 0; n < 4; ++n)
      bb[n] = *(const short8*)&LB[(wc * 64 + n * 16 + r) * BK + sl * 8];
    __builtin_amdgcn_s_setprio(1);
#pragma unroll
    for (int m = 0; m < 8; ++m)
#pragma unroll
      for (int n = 0; n < 4; ++n)
        acc[m][n] = __builtin_amdgcn_mfma_f32_16x16x32_bf16(a[m], bb[n], acc[m][n], 0, 0, 0);
    __builtin_amdgcn_s_setprio(0);
  };

  // Prologue: 3 K-tiles in flight; ensure kt0 landed (drain oldest 4 of 12).
  stage(0); stage(1); stage(2);
  WAITVM(8);
  BARRIER();

  // Main loop: compute kt, prefetch kt+3 into buf[(kt+3)&3] (= buf[(kt-1)&3],
  // whose reads completed before the previous barrier). End-of-iter vmcnt(8)
  // leaves kt+2,kt+3 (8 loads) outstanding and guarantees kt+1 landed.
#pragma unroll 1
  for (int kt = 0; kt < NKT - 3; ++kt) {
    stage(kt + 3);
    compute(kt);
    WAITVM(8);
    BARRIER();
  }
  compute(NKT - 3);
  WAITVM(4);
  BARRIER();
  compute(NKT - 2);
  WAITVM(0);
  BARRIER();
  compute(NKT - 1);
  BARRIER();  // all LDS reads done -> safe to reuse LDS for reduction

  // ---- fused epilogue ----
  // mse = (sx[row] + sy[col] - 2*cross)/D. Fold: rowmin = (sx + min(sy-2c))/D,
  // colmin = (sy + min(sx-2c))/D.  C/D map: col = r, row = q*4 + j.
  float* red = (float*)&lds[0][0][0];  // [0,1024) row side (4 wc), [1024,1536) col side (2 wr)

  float sy[4];
#pragma unroll
  for (int n = 0; n < 4; ++n) sy[n] = sqy[br0 + wc * 64 + n * 16 + r];

  // row side: min over n (frags) then over r lanes
#pragma unroll
  for (int m = 0; m < 8; ++m) {
#pragma unroll
    for (int j = 0; j < 4; ++j) {
      float v = sy[0] - 2.0f * acc[m][0][j];
#pragma unroll
      for (int n = 1; n < 4; ++n) v = fminf(v, sy[n] - 2.0f * acc[m][n][j]);
      v = fminf(v, __shfl_xor(v, 1));
      v = fminf(v, __shfl_xor(v, 2));
      v = fminf(v, __shfl_xor(v, 4));
      v = fminf(v, __shfl_xor(v, 8));
      if (r == 0) red[wc * 256 + wr * 128 + m * 16 + q * 4 + j] = v;
    }
  }

  // col side: needs sx per (m,j) row; min over m,j then over q lanes
  float sxr[8][4];
#pragma unroll
  for (int m = 0; m < 8; ++m)
#pragma unroll
    for (int j = 0; j < 4; ++j)
      sxr[m][j] = sqx[ar0 + wr * 128 + m * 16 + q * 4 + j];
#pragma unroll
  for (int n = 0; n < 4; ++n) {
    float v = sxr[0][0] - 2.0f * acc[0][n][0];
#pragma unroll
    for (int m = 0; m < 8; ++m)
#pragma unroll
      for (int j = 0; j < 4; ++j)
        v = fminf(v, sxr[m][j] - 2.0f * acc[m][n][j]);
    v = fminf(v, __shfl_xor(v, 16));
    v = fminf(v, __shfl_xor(v, 32));
    if (q == 0) red[1024 + wr * 256 + wc * 64 + n * 16 + r] = v;
  }
  __syncthreads();

  const float inv_d = 1.0f / (float)D_SZ;
  if (tid < 256) {
    float v = fminf(fminf(red[tid], red[256 + tid]), fminf(red[512 + tid], red[768 + tid]));
    v = (sqx[ar0 + tid] + v) * inv_d;
    atomicMin((int*)&rowmin[ar0 + tid], __float_as_int(v));  // mse > 0: int order == float order
  } else {
    const int c = tid - 256;
    float v = fminf(red[1024 + c], red[1280 + c]);
    v = (sqy[br0 + c] + v) * inv_d;
    atomicMin((int*)&colmin[br0 + c], __float_as_int(v));
  }
}

// Pass 3: mean of the 16384 mins -> scalar
extern "C" __global__ __launch_bounds__(256)
void final_k(const float* __restrict__ mins, float* __restrict__ out) {
  float s = 0.f;
  for (int i = threadIdx.x; i < 2 * B_SZ; i += 256) s += mins[i];
#pragma unroll
  for (int m = 1; m < 64; m <<= 1) s += __shfl_xor(s, m);
  __shared__ float red[4];
  if ((threadIdx.x & 63) == 0) red[threadIdx.x >> 6] = s;
  __syncthreads();
  if (threadIdx.x == 0)
    out[0] = (red[0] + red[1] + red[2] + red[3]) * (1.0f / (float)(2 * B_SZ));
}

extern "C" void kernel_launch(void* const* d_in, const int* in_sizes, int n_in,
                              void* d_out, int out_size, void* d_ws, size_t ws_size,
                              hipStream_t stream) {
  const float* X = (const float*)d_in[0];
  const float* Y = (const float*)d_in[1];
  char* ws = (char*)d_ws;
  ushort* Xb = (ushort*)ws;                                   // 16 MB
  ushort* Yb = (ushort*)(ws + (size_t)16 * 1024 * 1024);      // 16 MB
  float* sq  = (float*)(ws + (size_t)32 * 1024 * 1024);       // sqx[8192] ++ sqy[8192]
  float* mins = sq + 2 * B_SZ;                                // rowmin[8192] ++ colmin[8192]
  float* out = (float*)d_out;

  prep_k<<<2 * B_SZ, 256, 0, stream>>>(X, Y, Xb, Yb, sq, mins);
  gemm_min_k<<<dim3(B_SZ / BM, B_SZ / BN), 512, 0, stream>>>(Xb, Yb, sq, sq + B_SZ,
                                                             mins, mins + B_SZ);
  final_k<<<1, 256, 0, stream>>>(mins, out);
}

// Round 5
// 174.874 us; speedup vs baseline: 1.2659x; 1.0043x over previous
//
#include <hip/hip_runtime.h>
#include <hip/hip_bf16.h>
#include <stdint.h>

#define B_SZ 8192
#define D_SZ 1024
#define BM 256
#define BN 256
#define BK 32
#define NKT (D_SZ / BK)  // 32 K-tiles

typedef __attribute__((ext_vector_type(4))) float f32x4;
typedef __attribute__((ext_vector_type(8))) short short8;

#define WAITVM(n) asm volatile("s_waitcnt vmcnt(" #n ")" ::: "memory")

__device__ __forceinline__ ushort f2bf(float f) {
  union { float f; uint32_t u; } c; c.f = f;
  uint32_t u = c.u;
  return (ushort)((u + 0x7fffu + ((u >> 16) & 1u)) >> 16);  // RNE
}

__device__ __forceinline__ void gload_lds16(const ushort* g, void* l) {
  __builtin_amdgcn_global_load_lds(
      (const __attribute__((address_space(1))) void*)g,
      (__attribute__((address_space(3))) void*)l, 16, 0, 0);
}

// Pass 1: fp32 -> bf16 conversion, fp32 row sum-of-squares, init mins to +inf.
extern "C" __global__ __launch_bounds__(256)
void prep_k(const float* __restrict__ X, const float* __restrict__ Y,
            ushort* __restrict__ Xb, ushort* __restrict__ Yb,
            float* __restrict__ sq, float* __restrict__ mins) {
  const int b = blockIdx.x;
  const int t = threadIdx.x;
  const int row = b & (B_SZ - 1);
  const float* src = (b < B_SZ) ? X : Y;
  ushort* dst = (b < B_SZ) ? Xb : Yb;
  const float4 v = reinterpret_cast<const float4*>(src + (size_t)row * D_SZ)[t];
  float ss = v.x * v.x + v.y * v.y + v.z * v.z + v.w * v.w;
  ushort4 o;
  o.x = f2bf(v.x); o.y = f2bf(v.y); o.z = f2bf(v.z); o.w = f2bf(v.w);
  reinterpret_cast<ushort4*>(dst + (size_t)row * D_SZ)[t] = o;
#pragma unroll
  for (int m = 1; m < 64; m <<= 1) ss += __shfl_xor(ss, m);
  __shared__ float red[4];
  if ((t & 63) == 0) red[t >> 6] = ss;
  __syncthreads();
  if (t == 0) {
    sq[b] = red[0] + red[1] + red[2] + red[3];
    mins[b] = __builtin_inff();
  }
}

// Pass 2: 256x256 tile, BK=32, 8 waves (2x4), 4-deep LDS ring, counted vmcnt,
// 2 fine phases per K-tile (T3-style): {reads+stage | barrier | 16 MFMA} x2.
// Per wave: 128x64 output = acc[8][4] of 16x16x32 bf16 fragments.
// LDS swizzle (verified r4, conflicts=0): slot s of row holds k-chunk s^((row>>1)&3),
// applied on the global source (gload dest linear) and on the ds_read slot.
extern "C" __global__ __launch_bounds__(512, 2)
void gemm_min_k(const ushort* __restrict__ Xb, const ushort* __restrict__ Yb,
                const float* __restrict__ sqx, const float* __restrict__ sqy,
                float* __restrict__ rowmin, float* __restrict__ colmin) {
  __shared__ ushort lds[4][2][BM * BK];  // 4 ring bufs x {A,B} x 256x32 bf16 = 128 KiB

  const int tid  = threadIdx.x;
  const int wave = tid >> 6;
  const int lane = tid & 63;
  const int q    = lane >> 4;    // 0..3
  const int r    = lane & 15;    // 0..15
  const int wr   = wave >> 2;    // 0..1  (M half)
  const int wc   = wave & 3;     // 0..3  (N quarter)
  const int sl   = q ^ ((r >> 1) & 3);  // swizzled ds_read slot

  const size_t ar0 = (size_t)blockIdx.x * BM;
  const size_t br0 = (size_t)blockIdx.y * BN;
  const ushort* Ab = Xb + ar0 * D_SZ;
  const ushort* Bb = Yb + br0 * D_SZ;

  // staging: per operand per K-tile = 256x32 bf16 = 16 KiB = 2 gloads/thread.
  // chunk c -> row=c>>2, slot=c&3; global k-chunk = slot ^ ((row>>1)&3).
  const int c0 = wave * 64 + lane;
  const int c1 = c0 + 512;
  const int r0 = c0 >> 2, r1 = c1 >> 2;
  const int s0 = (c0 & 3) ^ ((r0 >> 1) & 3);
  const int s1 = (c1 & 3) ^ ((r1 >> 1) & 3);
  const size_t ga0 = (size_t)r0 * D_SZ + s0 * 8;
  const size_t ga1 = (size_t)r1 * D_SZ + s1 * 8;
  const int ldsoff0 = wave * 1024;           // bytes
  const int ldsoff1 = wave * 1024 + 8192;

  f32x4 acc[8][4];
#pragma unroll
  for (int m = 0; m < 8; ++m)
#pragma unroll
    for (int n = 0; n < 4; ++n)
      acc[m][n] = (f32x4){0.f, 0.f, 0.f, 0.f};

  auto stageA = [&](int kt) {
    const int s = kt & 3; const int ko = kt * BK;
    gload_lds16(Ab + ga0 + ko, (char*)&lds[s][0][0] + ldsoff0);
    gload_lds16(Ab + ga1 + ko, (char*)&lds[s][0][0] + ldsoff1);
  };
  auto stageB = [&](int kt) {
    const int s = kt & 3; const int ko = kt * BK;
    gload_lds16(Bb + ga0 + ko, (char*)&lds[s][1][0] + ldsoff0);
    gload_lds16(Bb + ga1 + ko, (char*)&lds[s][1][0] + ldsoff1);
  };

  short8 a[8], bb[4];
  auto ldA = [&](int kt, int m0) {
    const ushort* LA = &lds[kt & 3][0][0];
#pragma unroll
    for (int m = 0; m < 4; ++m)
      a[m0 + m] = *(const short8*)&LA[(wr * 128 + (m0 + m) * 16 + r) * BK + sl * 8];
  };
  auto ldB = [&](int kt) {
    const ushort* LB = &lds[kt & 3][1][0];
#pragma unroll
    for (int n = 0; n < 4; ++n)
      bb[n] = *(const short8*)&LB[(wc * 64 + n * 16 + r) * BK + sl * 8];
  };
  auto mf = [&](int m0) {
    __builtin_amdgcn_s_setprio(1);
#pragma unroll
    for (int m = 0; m < 4; ++m)
#pragma unroll
      for (int n = 0; n < 4; ++n)
        acc[m0 + m][n] =
            __builtin_amdgcn_mfma_f32_16x16x32_bf16(a[m0 + m], bb[n], acc[m0 + m][n], 0, 0, 0);
    __builtin_amdgcn_s_setprio(0);
  };

  // Prologue: tiles 0,1,2 staged (12 loads); vmcnt(8) forces tile 0 landed.
  stageA(0); stageB(0); stageA(1); stageB(1); stageA(2); stageB(2);
  WAITVM(8);
  __builtin_amdgcn_s_barrier();

  // Main loop: 2 phases per K-tile. vmcnt(8) per tile leaves tiles kt+2,kt+3
  // (8 loads) in flight and forces kt+1 landed before its reads.
#pragma unroll 1
  for (int kt = 0; kt < NKT - 3; ++kt) {
    // P0: reads for m0-3 + stage A(kt+3) -> slot (kt-1)&3 (reads done last tile)
    ldA(kt, 0); ldB(kt); stageA(kt + 3);
    __builtin_amdgcn_s_barrier();
    mf(0);
    // P1: reads for m4-7 + stage B(kt+3)
    ldA(kt, 4); stageB(kt + 3);
    WAITVM(8);
    __builtin_amdgcn_s_barrier();
    mf(4);
    __builtin_amdgcn_s_barrier();  // end-of-tile: slot (kt)&3 reads all done
  }
  // Tail: kt = NKT-3 (no stage; drain to 4), NKT-2 (drain to 0), NKT-1.
  {
    const int kt = NKT - 3;
    ldA(kt, 0); ldB(kt);
    __builtin_amdgcn_s_barrier();
    mf(0);
    ldA(kt, 4);
    WAITVM(4);
    __builtin_amdgcn_s_barrier();
    mf(4);
    __builtin_amdgcn_s_barrier();
  }
  {
    const int kt = NKT - 2;
    ldA(kt, 0); ldB(kt);
    __builtin_amdgcn_s_barrier();
    mf(0);
    ldA(kt, 4);
    WAITVM(0);
    __builtin_amdgcn_s_barrier();
    mf(4);
    __builtin_amdgcn_s_barrier();
  }
  {
    const int kt = NKT - 1;
    ldA(kt, 0); ldB(kt);
    __builtin_amdgcn_s_barrier();
    mf(0);
    ldA(kt, 4);
    __builtin_amdgcn_s_barrier();
    mf(4);
    __builtin_amdgcn_s_barrier();  // all LDS reads done -> safe to reuse LDS
  }

  // ---- fused epilogue (verified r4, absmax 0) ----
  // rowmin_part = min_n (sy - 2c)  (sx added at write), colmin_part = min_m (sx - 2c).
  float* red = (float*)&lds[0][0][0];  // [0,1024) row side, [1024,1536) col side

  float sy[4];
#pragma unroll
  for (int n = 0; n < 4; ++n) sy[n] = sqy[br0 + wc * 64 + n * 16 + r];

  float cm[4];
#pragma unroll
  for (int n = 0; n < 4; ++n) cm[n] = __builtin_inff();

#pragma unroll
  for (int m = 0; m < 8; ++m) {
    float sxm[4];
#pragma unroll
    for (int j = 0; j < 4; ++j)
      sxm[j] = sqx[ar0 + wr * 128 + m * 16 + q * 4 + j];
#pragma unroll
    for (int j = 0; j < 4; ++j) {
      float best = __builtin_inff();
#pragma unroll
      for (int n = 0; n < 4; ++n) {
        const float c2 = 2.0f * acc[m][n][j];
        best = fminf(best, sy[n] - c2);
        cm[n] = fminf(cm[n], sxm[j] - c2);
      }
      float v = best;
      v = fminf(v, __shfl_xor(v, 1));
      v = fminf(v, __shfl_xor(v, 2));
      v = fminf(v, __shfl_xor(v, 4));
      v = fminf(v, __shfl_xor(v, 8));
      if (r == 0) red[wc * 256 + wr * 128 + m * 16 + q * 4 + j] = v;
    }
  }
#pragma unroll
  for (int n = 0; n < 4; ++n) {
    float v = cm[n];
    v = fminf(v, __shfl_xor(v, 16));
    v = fminf(v, __shfl_xor(v, 32));
    if (q == 0) red[1024 + wr * 256 + wc * 64 + n * 16 + r] = v;
  }
  __syncthreads();

  const float inv_d = 1.0f / (float)D_SZ;
  if (tid < 256) {
    float v = fminf(fminf(red[tid], red[256 + tid]), fminf(red[512 + tid], red[768 + tid]));
    v = (sqx[ar0 + tid] + v) * inv_d;
    atomicMin((int*)&rowmin[ar0 + tid], __float_as_int(v));  // mse > 0: int order == float order
  } else {
    const int c = tid - 256;
    float v = fminf(red[1024 + c], red[1280 + c]);
    v = (sqy[br0 + c] + v) * inv_d;
    atomicMin((int*)&colmin[br0 + c], __float_as_int(v));
  }
}

// Pass 3: mean of the 16384 mins -> scalar
extern "C" __global__ __launch_bounds__(256)
void final_k(const float* __restrict__ mins, float* __restrict__ out) {
  float s = 0.f;
  for (int i = threadIdx.x; i < 2 * B_SZ; i += 256) s += mins[i];
#pragma unroll
  for (int m = 1; m < 64; m <<= 1) s += __shfl_xor(s, m);
  __shared__ float red[4];
  if ((threadIdx.x & 63) == 0) red[threadIdx.x >> 6] = s;
  __syncthreads();
  if (threadIdx.x == 0)
    out[0] = (red[0] + red[1] + red[2] + red[3]) * (1.0f / (float)(2 * B_SZ));
}

extern "C" void kernel_launch(void* const* d_in, const int* in_sizes, int n_in,
                              void* d_out, int out_size, void* d_ws, size_t ws_size,
                              hipStream_t stream) {
  const float* X = (const float*)d_in[0];
  const float* Y = (const float*)d_in[1];
  char* ws = (char*)d_ws;
  ushort* Xb = (ushort*)ws;                                   // 16 MB
  ushort* Yb = (ushort*)(ws + (size_t)16 * 1024 * 1024);      // 16 MB
  float* sq  = (float*)(ws + (size_t)32 * 1024 * 1024);       // sqx[8192] ++ sqy[8192]
  float* mins = sq + 2 * B_SZ;                                // rowmin[8192] ++ colmin[8192]
  float* out = (float*)d_out;

  prep_k<<<2 * B_SZ, 256, 0, stream>>>(X, Y, Xb, Yb, sq, mins);
  gemm_min_k<<<dim3(B_SZ / BM, B_SZ / BN), 512, 0, stream>>>(Xb, Yb, sq, sq + B_SZ,
                                                             mins, mins + B_SZ);
  final_k<<<1, 256, 0, stream>>>(mins, out);
}

// Round 6
// 174.290 us; speedup vs baseline: 1.2701x; 1.0034x over previous
//
#include <hip/hip_runtime.h>
#include <hip/hip_bf16.h>
#include <stdint.h>

#define B_SZ 8192
#define D_SZ 1024
#define BM 256
#define BN 256
#define BK 64
#define NKT (D_SZ / BK)  // 16 K-tiles

typedef __attribute__((ext_vector_type(4))) float f32x4;
typedef __attribute__((ext_vector_type(8))) short short8;

#define WAITVM(n) asm volatile("s_waitcnt vmcnt(" #n ")" ::: "memory")

__device__ __forceinline__ ushort f2bf(float f) {
  union { float f; uint32_t u; } c; c.f = f;
  uint32_t u = c.u;
  return (ushort)((u + 0x7fffu + ((u >> 16) & 1u)) >> 16);  // RNE
}

__device__ __forceinline__ void gload_lds16(const ushort* g, void* l) {
  __builtin_amdgcn_global_load_lds(
      (const __attribute__((address_space(1))) void*)g,
      (__attribute__((address_space(3))) void*)l, 16, 0, 0);
}

// Pass 1: fp32 -> bf16 conversion, fp32 row sum-of-squares, init mins to +inf.
extern "C" __global__ __launch_bounds__(256)
void prep_k(const float* __restrict__ X, const float* __restrict__ Y,
            ushort* __restrict__ Xb, ushort* __restrict__ Yb,
            float* __restrict__ sq, float* __restrict__ mins) {
  const int b = blockIdx.x;
  const int t = threadIdx.x;
  const int row = b & (B_SZ - 1);
  const float* src = (b < B_SZ) ? X : Y;
  ushort* dst = (b < B_SZ) ? Xb : Yb;
  const float4 v = reinterpret_cast<const float4*>(src + (size_t)row * D_SZ)[t];
  float ss = v.x * v.x + v.y * v.y + v.z * v.z + v.w * v.w;
  ushort4 o;
  o.x = f2bf(v.x); o.y = f2bf(v.y); o.z = f2bf(v.z); o.w = f2bf(v.w);
  reinterpret_cast<ushort4*>(dst + (size_t)row * D_SZ)[t] = o;
#pragma unroll
  for (int m = 1; m < 64; m <<= 1) ss += __shfl_xor(ss, m);
  __shared__ float red[4];
  if ((t & 63) == 0) red[t >> 6] = ss;
  __syncthreads();
  if (t == 0) {
    sq[b] = red[0] + red[1] + red[2] + red[3];
    mins[b] = __builtin_inff();
  }
}

// Pass 2: 256x256 tile, BK=64, 8 waves (2x4), 2-slot LDS dbuf, m201-style
// 4 fine phases per K-tile: {4-8 ds_read || stage -> barrier -> 16 MFMA -> barrier}.
// Phase split by (k-half ks, m-half mh). Per wave: 128x64 out = acc[8][4].
// Swizzle: row of 8 16B-chunks; stored slot s holds logical chunk s^(row&7).
// Applied on global source (gload dest linear, rule 21) and on ds_read slot.
extern "C" __global__ __launch_bounds__(512, 2)
void gemm_min_k(const ushort* __restrict__ Xb, const ushort* __restrict__ Yb,
                const float* __restrict__ sqx, const float* __restrict__ sqy,
                float* __restrict__ rowmin, float* __restrict__ colmin) {
  __shared__ ushort lds[2][2][BM * BK];  // 2 slots x {A,B} x 256x64 bf16 = 128 KiB

  const int tid  = threadIdx.x;
  const int wave = tid >> 6;
  const int lane = tid & 63;
  const int q    = lane >> 4;    // 0..3
  const int r    = lane & 15;    // 0..15
  const int wr   = wave >> 2;    // 0..1  (M half)
  const int wc   = wave & 3;     // 0..3  (N quarter)

  const size_t ar0 = (size_t)blockIdx.x * BM;
  const size_t br0 = (size_t)blockIdx.y * BN;
  const ushort* Ab = Xb + ar0 * D_SZ;
  const ushort* Bb = Yb + br0 * D_SZ;

  // staging: tile/operand = 256 rows x 8 chunks(16B) = 32 KB; half = 128 rows.
  // thread's chunk (per half, per i): g = h*1024 + i*512 + wave*64 + lane
  //   -> row = h*128 + i*64 + grow, slot = lane&7, logical = slot ^ (row&7).
  const int grow = wave * 8 + (lane >> 3);
  const int lc   = (lane & 7) ^ (grow & 7);

  auto stage_half = [&](int t, int op, int h) {
    const ushort* G = op ? Bb : Ab;
    char* L = (char*)&lds[t & 1][op][0];
#pragma unroll
    for (int i = 0; i < 2; ++i) {
      const int row = h * 128 + i * 64 + grow;
      gload_lds16(G + (size_t)row * D_SZ + t * BK + lc * 8,
                  L + (h * 1024 + i * 512 + wave * 64) * 16);
    }
  };

  f32x4 acc[8][4];
#pragma unroll
  for (int m = 0; m < 8; ++m)
#pragma unroll
    for (int n = 0; n < 4; ++n)
      acc[m][n] = (f32x4){0.f, 0.f, 0.f, 0.f};

  short8 aA[4], aB[4], bb[4];
  auto ldA = [&](int t, int ks, int mh, short8* dst) {
    const ushort* L = &lds[t & 1][0][0];
#pragma unroll
    for (int m = 0; m < 4; ++m) {
      const int rr = wr * 128 + (mh * 4 + m) * 16 + r;
      const int c = ks * 4 + q;
      dst[m] = *(const short8*)&L[rr * 64 + ((c ^ (rr & 7)) * 8)];
    }
  };
  auto ldB = [&](int t, int ks) {
    const ushort* L = &lds[t & 1][1][0];
#pragma unroll
    for (int n = 0; n < 4; ++n) {
      const int rr = wc * 64 + n * 16 + r;
      const int c = ks * 4 + q;
      bb[n] = *(const short8*)&L[rr * 64 + ((c ^ (rr & 7)) * 8)];
    }
  };
  auto mf4 = [&](const short8* av, int mh) {
    __builtin_amdgcn_s_setprio(1);
#pragma unroll
    for (int m = 0; m < 4; ++m)
#pragma unroll
      for (int n = 0; n < 4; ++n)
        acc[mh * 4 + m][n] =
            __builtin_amdgcn_mfma_f32_16x16x32_bf16(av[m], bb[n], acc[mh * 4 + m][n], 0, 0, 0);
    __builtin_amdgcn_s_setprio(0);
  };

  // Prologue: stage tile 0 fully (8 loads), drain, sync.
  stage_half(0, 0, 0); stage_half(0, 0, 1);
  stage_half(0, 1, 0); stage_half(0, 1, 1);
  WAITVM(0);
  __builtin_amdgcn_s_barrier();

  // Main loop. Tile t's loads were issued during tile t-1 (A at P1, B at P2)
  // and drained by the single vmcnt(0) at t-1's P4 (~650+ cyc after issue).
#pragma unroll 1
  for (int t = 0; t < NKT - 1; ++t) {
    // P1: ks0 m-lo (8 reads) + stage A(t+1)
    ldA(t, 0, 0, aA); ldB(t, 0);
    stage_half(t + 1, 0, 0); stage_half(t + 1, 0, 1);
    __builtin_amdgcn_s_barrier();
    mf4(aA, 0);
    __builtin_amdgcn_s_barrier();
    // P2: ks0 m-hi (4 reads) + stage B(t+1)
    ldA(t, 0, 1, aB);
    stage_half(t + 1, 1, 0); stage_half(t + 1, 1, 1);
    __builtin_amdgcn_s_barrier();
    mf4(aB, 1);
    __builtin_amdgcn_s_barrier();
    // P3: ks1 m-lo (8 reads)
    ldA(t, 1, 0, aA); ldB(t, 1);
    __builtin_amdgcn_s_barrier();
    mf4(aA, 0);
    __builtin_amdgcn_s_barrier();
    // P4: ks1 m-hi (4 reads); drain t+1's 8 loads before next tile's reads
    ldA(t, 1, 1, aB);
    WAITVM(0);
    __builtin_amdgcn_s_barrier();
    mf4(aB, 1);
    __builtin_amdgcn_s_barrier();
  }
  // Peeled last tile (no stage, no vmcnt)
  {
    const int t = NKT - 1;
    ldA(t, 0, 0, aA); ldB(t, 0);
    __builtin_amdgcn_s_barrier();
    mf4(aA, 0);
    __builtin_amdgcn_s_barrier();
    ldA(t, 0, 1, aB);
    __builtin_amdgcn_s_barrier();
    mf4(aB, 1);
    __builtin_amdgcn_s_barrier();
    ldA(t, 1, 0, aA); ldB(t, 1);
    __builtin_amdgcn_s_barrier();
    mf4(aA, 0);
    __builtin_amdgcn_s_barrier();
    ldA(t, 1, 1, aB);
    __builtin_amdgcn_s_barrier();
    mf4(aB, 1);
    __builtin_amdgcn_s_barrier();  // all LDS reads done -> safe to reuse LDS
  }

  // ---- fused epilogue (verified r4/r5, absmax 0) ----
  // rowmin_part = min_n (sy - 2c)  (sx added at write), colmin_part = min_m (sx - 2c).
  // C/D map: col = r (within frag n), row = q*4 + j (within frag m).
  float* red = (float*)&lds[0][0][0];  // [0,1024) row side, [1024,1536) col side

  float sy[4];
#pragma unroll
  for (int n = 0; n < 4; ++n) sy[n] = sqy[br0 + wc * 64 + n * 16 + r];

  float cm[4];
#pragma unroll
  for (int n = 0; n < 4; ++n) cm[n] = __builtin_inff();

#pragma unroll
  for (int m = 0; m < 8; ++m) {
    float sxm[4];
#pragma unroll
    for (int j = 0; j < 4; ++j)
      sxm[j] = sqx[ar0 + wr * 128 + m * 16 + q * 4 + j];
#pragma unroll
    for (int j = 0; j < 4; ++j) {
      float best = __builtin_inff();
#pragma unroll
      for (int n = 0; n < 4; ++n) {
        const float c2 = 2.0f * acc[m][n][j];
        best = fminf(best, sy[n] - c2);
        cm[n] = fminf(cm[n], sxm[j] - c2);
      }
      float v = best;
      v = fminf(v, __shfl_xor(v, 1));
      v = fminf(v, __shfl_xor(v, 2));
      v = fminf(v, __shfl_xor(v, 4));
      v = fminf(v, __shfl_xor(v, 8));
      if (r == 0) red[wc * 256 + wr * 128 + m * 16 + q * 4 + j] = v;
    }
  }
#pragma unroll
  for (int n = 0; n < 4; ++n) {
    float v = cm[n];
    v = fminf(v, __shfl_xor(v, 16));
    v = fminf(v, __shfl_xor(v, 32));
    if (q == 0) red[1024 + wr * 256 + wc * 64 + n * 16 + r] = v;
  }
  __syncthreads();

  const float inv_d = 1.0f / (float)D_SZ;
  if (tid < 256) {
    float v = fminf(fminf(red[tid], red[256 + tid]), fminf(red[512 + tid], red[768 + tid]));
    v = (sqx[ar0 + tid] + v) * inv_d;
    atomicMin((int*)&rowmin[ar0 + tid], __float_as_int(v));  // mse > 0: int order == float order
  } else {
    const int c = tid - 256;
    float v = fminf(red[1024 + c], red[1280 + c]);
    v = (sqy[br0 + c] + v) * inv_d;
    atomicMin((int*)&colmin[br0 + c], __float_as_int(v));
  }
}

// Pass 3: mean of the 16384 mins -> scalar
extern "C" __global__ __launch_bounds__(256)
void final_k(const float* __restrict__ mins, float* __restrict__ out) {
  float s = 0.f;
  for (int i = threadIdx.x; i < 2 * B_SZ; i += 256) s += mins[i];
#pragma unroll
  for (int m = 1; m < 64; m <<= 1) s += __shfl_xor(s, m);
  __shared__ float red[4];
  if ((threadIdx.x & 63) == 0) red[threadIdx.x >> 6] = s;
  __syncthreads();
  if (threadIdx.x == 0)
    out[0] = (red[0] + red[1] + red[2] + red[3]) * (1.0f / (float)(2 * B_SZ));
}

extern "C" void kernel_launch(void* const* d_in, const int* in_sizes, int n_in,
                              void* d_out, int out_size, void* d_ws, size_t ws_size,
                              hipStream_t stream) {
  const float* X = (const float*)d_in[0];
  const float* Y = (const float*)d_in[1];
  char* ws = (char*)d_ws;
  ushort* Xb = (ushort*)ws;                                   // 16 MB
  ushort* Yb = (ushort*)(ws + (size_t)16 * 1024 * 1024);      // 16 MB
  float* sq  = (float*)(ws + (size_t)32 * 1024 * 1024);       // sqx[8192] ++ sqy[8192]
  float* mins = sq + 2 * B_SZ;                                // rowmin[8192] ++ colmin[8192]
  float* out = (float*)d_out;

  prep_k<<<2 * B_SZ, 256, 0, stream>>>(X, Y, Xb, Yb, sq, mins);
  gemm_min_k<<<dim3(B_SZ / BM, B_SZ / BN), 512, 0, stream>>>(Xb, Yb, sq, sq + B_SZ,
                                                             mins, mins + B_SZ);
  final_k<<<1, 256, 0, stream>>>(mins, out);
}